// Round 3
// baseline (11224.877 us; speedup 1.0000x reference)
//
#include <hip/hip_runtime.h>
#include <cstdint>
#include <cstddef>

// ---------------------------------------------------------------------------
// GCN(Cheb K=2, x2) -> 3-layer LSTM -> MLP head, MI355X gfx950.
// R3: (a) weight fragments pinned in VGPRs via asm("" : "+v") — R2's VGPR=80
//     proved the compiler was re-loading weights every step (L1-BW bound);
//     (b) lstmB pair-exchange rebuilt as fence-free tagged atomics
//     (u32 = tag<<16 | bf16, relaxed agent scope, parity double-buffered)
//     — eliminates per-step buffer_wbl2 from __threadfence release.
// ---------------------------------------------------------------------------

#define T_DIM 32
#define F_DIMC 16
#define NNODE 15872
#define EDGES 200000
#define BATCH 256
#define SEQL 512
#define TN (T_DIM * NNODE)   // 507904
#define TE (T_DIM * EDGES)   // 6400000

typedef unsigned short ushortT;
typedef __bf16 bf16_t;
typedef bf16_t bf16x8 __attribute__((ext_vector_type(8)));
typedef float f32x4 __attribute__((ext_vector_type(4)));
typedef uint32_t u32x4 __attribute__((ext_vector_type(4)));

__device__ __forceinline__ ushortT f2bf(float f) {
  union { float f; unsigned u; } v; v.f = f;
  unsigned u = v.u;
  u += 0x7fffu + ((u >> 16) & 1u);
  return (ushortT)(u >> 16);
}
__device__ __forceinline__ float fsig(float x) { return 1.0f / (1.0f + __expf(-x)); }
__device__ __forceinline__ float ftanh(float x) {
  float e = __expf(2.0f * x);
  return 1.0f - 2.0f / (e + 1.0f);
}
#define PIN(v) asm volatile("" : "+v"(v))

// ---------------------------------------------------------------------------
// Weight prep: Wcat1 [256][128] = [wih1(62,pad2) | whh1(64)]
//              Wcat2 [512][192] = [wih2(64) | whh2(128)]
//              Wcat3 [1024][384] = [wih3(128) | whh3(256)]   (bf16, row = gate)
// ---------------------------------------------------------------------------
__global__ void k_wprep(const float* __restrict__ w1i, const float* __restrict__ w1h,
                        const float* __restrict__ w2i, const float* __restrict__ w2h,
                        const float* __restrict__ w3i, const float* __restrict__ w3h,
                        ushortT* __restrict__ Wcat) {
  int id = blockIdx.x * 256 + threadIdx.x;
  if (id >= 524288) return;
  float v;
  if (id < 32768) {
    int g = id >> 7, k = id & 127;
    v = (k < 62) ? w1i[g * 62 + k] : ((k >= 64) ? w1h[g * 64 + (k - 64)] : 0.0f);
  } else if (id < 131072) {
    int j = id - 32768; int g = j / 192, k = j % 192;
    v = (k < 64) ? w2i[g * 64 + k] : w2h[g * 128 + (k - 64)];
  } else {
    int j = id - 131072; int g = j / 384, k = j % 384;
    v = (k < 128) ? w3i[g * 128 + k] : w3h[g * 256 + (k - 128)];
  }
  Wcat[id] = f2bf(v);
}

// x [N][F][T] -> xt [T][N][F], LDS-tiled per node row
__global__ void k_transpose(const float* __restrict__ x, float* __restrict__ xt) {
  __shared__ float s[528];  // 16 x 33
  int n = blockIdx.x;
  int tid = threadIdx.x;
  for (int i = tid; i < 512; i += 256) {
    s[(i >> 5) * 33 + (i & 31)] = x[(size_t)n * 512 + i];
  }
  __syncthreads();
  for (int i = tid; i < 512; i += 256) {
    int t = i >> 4, f = i & 15;
    xt[((size_t)t * NNODE + n) * 16 + f] = s[f * 33 + t];
  }
}

// per-edge: deg[src] += w ; counts[dst] += 1
__global__ void k_degcount(const int* __restrict__ ei, const float* __restrict__ ew,
                           float* __restrict__ deg, int* __restrict__ counts) {
  int id = blockIdx.x * 256 + threadIdx.x;
  if (id >= TE) return;
  int t = id / EDGES, e = id % EDGES;
  int src = ei[(2 * t) * EDGES + e];
  int dst = ei[(2 * t + 1) * EDGES + e];
  atomicAdd(&deg[t * NNODE + src], ew[id]);
  atomicAdd(&counts[t * NNODE + dst], 1);
}

__global__ void k_dinv(float* __restrict__ deg) {
  int id = blockIdx.x * 256 + threadIdx.x;
  if (id >= TN) return;
  float d = deg[id];
  deg[id] = (d > 0.0f) ? rsqrtf(d) : 0.0f;
}

// block-local exclusive scan of counts (256-chunks), chunk totals out
__global__ void k_scanA(const int* __restrict__ counts, int* __restrict__ offs,
                        int* __restrict__ ctot) {
  __shared__ int s[256];
  int tid = threadIdx.x;
  int gid = blockIdx.x * 256 + tid;
  int v = counts[gid];
  s[tid] = v; __syncthreads();
  for (int off = 1; off < 256; off <<= 1) {
    int x = (tid >= off) ? s[tid - off] : 0;
    __syncthreads();
    s[tid] += x;
    __syncthreads();
  }
  offs[gid] = s[tid] - v;
  if (tid == 255) ctot[blockIdx.x] = s[255];
}

// single-block scan of 1984 chunk totals
__global__ void k_scanB(const int* __restrict__ ctot, int* __restrict__ cbase) {
  __shared__ int s[256];
  int tid = threadIdx.x;
  int carry = 0;
  for (int c = 0; c < 8; ++c) {
    int i = c * 256 + tid;
    int v = (i < 1984) ? ctot[i] : 0;
    s[tid] = v; __syncthreads();
    for (int off = 1; off < 256; off <<= 1) {
      int x = (tid >= off) ? s[tid - off] : 0;
      __syncthreads();
      s[tid] += x;
      __syncthreads();
    }
    if (i < 1984) cbase[i] = carry + s[tid] - v;
    int tot = s[255];
    __syncthreads();
    carry += tot;
  }
}

__global__ void k_scanC(int* __restrict__ offs, const int* __restrict__ cbase) {
  int id = blockIdx.x * 256 + threadIdx.x;
  if (id >= TN) return;
  offs[id] += cbase[id >> 8];
}

// scatter edges into CSR slots: csr_src[pos], csr_nrm[pos]
__global__ void k_fill(const int* __restrict__ ei, const float* __restrict__ ew,
                       const float* __restrict__ dinv, const int* __restrict__ offs,
                       int* __restrict__ fillc, int* __restrict__ csrs,
                       float* __restrict__ csrn) {
  int id = blockIdx.x * 256 + threadIdx.x;
  if (id >= TE) return;
  int t = id / EDGES, e = id % EDGES;
  int src = ei[(2 * t) * EDGES + e];
  int dst = ei[(2 * t + 1) * EDGES + e];
  int idx = t * NNODE + dst;
  int pos = offs[idx] + atomicAdd(&fillc[idx], 1);
  csrs[pos] = src;
  csrn[pos] = -dinv[t * NNODE + src] * ew[id] * dinv[idx];
}

__device__ __forceinline__ void fma4(float4& a, float sc, const float4 b) {
  a.x += sc * b.x; a.y += sc * b.y; a.z += sc * b.z; a.w += sc * b.w;
}

// gather (tx1) + combine: out = x@w0 + tx1@w1 + b [+leaky] ; mode1 writes xc bf16
__global__ void k_gc(const float* __restrict__ in, const int* __restrict__ offs,
                     const int* __restrict__ csrs, const float* __restrict__ csrn,
                     const float* __restrict__ w0, const float* __restrict__ w1,
                     const float* __restrict__ bias, float* __restrict__ outF,
                     ushortT* __restrict__ outX, int mode) {
  __shared__ float sw0[256], sw1[256], sb[16];
  int tid = threadIdx.x;
  sw0[tid] = w0[tid];
  sw1[tid] = w1[tid];
  if (tid < 16) sb[tid] = bias[tid];
  __syncthreads();
  int idx = blockIdx.x * 256 + tid;
  if (idx >= TN) return;
  int t = idx / NNODE, n = idx % NNODE;
  const float4* rowp = (const float4*)(in + (size_t)idx * 16);
  float4 x0 = rowp[0], x1 = rowp[1], x2 = rowp[2], x3 = rowp[3];
  float4 a0 = {0, 0, 0, 0}, a1 = {0, 0, 0, 0}, a2 = {0, 0, 0, 0}, a3 = {0, 0, 0, 0};
  int beg = offs[idx];
  int end = (idx == TN - 1) ? TE : offs[idx + 1];
  const float* base = in + (size_t)t * NNODE * 16;
  for (int p2 = beg; p2 < end; ++p2) {
    int s = csrs[p2];
    float nr = csrn[p2];
    const float4* rp = (const float4*)(base + (size_t)s * 16);
    fma4(a0, nr, rp[0]); fma4(a1, nr, rp[1]); fma4(a2, nr, rp[2]); fma4(a3, nr, rp[3]);
  }
  float xr[16], ar[16];
  *(float4*)&xr[0] = x0; *(float4*)&xr[4] = x1; *(float4*)&xr[8] = x2; *(float4*)&xr[12] = x3;
  *(float4*)&ar[0] = a0; *(float4*)&ar[4] = a1; *(float4*)&ar[8] = a2; *(float4*)&ar[12] = a3;
  float o[16];
#pragma unroll
  for (int j = 0; j < 16; ++j) o[j] = sb[j];
#pragma unroll
  for (int k = 0; k < 16; ++k) {
    float xv = xr[k], av = ar[k];
#pragma unroll
    for (int j = 0; j < 16; ++j) o[j] += xv * sw0[k * 16 + j] + av * sw1[k * 16 + j];
  }
  if (mode == 0) {
#pragma unroll
    for (int j = 0; j < 16; ++j) o[j] = (o[j] > 0.0f) ? o[j] : 0.01f * o[j];
    float4* op = (float4*)(outF + (size_t)idx * 16);
    op[0] = *(float4*)&o[0]; op[1] = *(float4*)&o[4];
    op[2] = *(float4*)&o[8]; op[3] = *(float4*)&o[12];
  } else {
    int bb = n / 62, ch = n % 62;
#pragma unroll
    for (int j = 0; j < 16; ++j)
      outX[((size_t)(bb * 512 + t * 16 + j)) * 64 + ch] = f2bf(o[j]);
  }
}

// ---------------------------------------------------------------------------
// LSTM stage A: layers 1+2. 16 blocks x 512 thr (8 waves).
// W1 frags (waves 0-3, 64 VGPR) + W2 frags (all waves, 96 VGPR) pinned.
// h2(t) written to h2hist [g][t][16][128] bf16 for stage B.
// ---------------------------------------------------------------------------
__global__ __launch_bounds__(512, 2) void k_lstmA(const ushortT* __restrict__ xc,
                                                  const ushortT* __restrict__ Wcat,
                                                  const float* __restrict__ b1g,
                                                  const float* __restrict__ b2g,
                                                  ushortT* __restrict__ h2hist) {
  __shared__ ushortT X1[2][16 * 72];
  __shared__ ushortT H1[2][16 * 72];
  __shared__ ushortT H2[2][16 * 136];
  __shared__ float C1[16 * 64];
  __shared__ float C2[16 * 128];
  int tid = threadIdx.x;
  int wv = tid >> 6, lane = tid & 63;
  int col = lane & 15, koff = (lane >> 4) * 8, m = lane & 15;
  int g = blockIdx.x;
  int bg = g * 16;
  const ushortT* W1 = Wcat;
  const ushortT* W2 = Wcat + 32768;

  bf16x8 w1r[4][4];
  if (wv < 4) {
#pragma unroll
    for (int q = 0; q < 4; ++q)
#pragma unroll
      for (int k = 0; k < 4; ++k) {
        w1r[q][k] = *reinterpret_cast<const bf16x8*>(
            &W1[(size_t)(q * 64 + wv * 16 + col) * 128 + k * 32 + koff]);
        PIN(w1r[q][k]);
      }
  }
  bf16x8 w2r[4][6];
#pragma unroll
  for (int q = 0; q < 4; ++q)
#pragma unroll
    for (int k = 0; k < 6; ++k) {
      w2r[q][k] = *reinterpret_cast<const bf16x8*>(
          &W2[(size_t)(q * 128 + wv * 16 + col) * 192 + k * 32 + koff]);
      PIN(w2r[q][k]);
    }
  float b1v[4] = {0, 0, 0, 0}, b2v[4];
  if (wv < 4) {
#pragma unroll
    for (int q = 0; q < 4; ++q) b1v[q] = b1g[q * 64 + wv * 16 + col];
  }
#pragma unroll
  for (int q = 0; q < 4; ++q) b2v[q] = b2g[q * 128 + wv * 16 + col];

  for (int i = tid; i < 2 * 16 * 72; i += 512) { X1[0][i] = 0; H1[0][i] = 0; }
  for (int i = tid; i < 2 * 16 * 136; i += 512) H2[0][i] = 0;
  for (int i = tid; i < 16 * 64; i += 512) C1[i] = 0.0f;
  for (int i = tid; i < 16 * 128; i += 512) C2[i] = 0.0f;
  __syncthreads();
  // prestage xc(t=0) into X1 parity 0 (waves 4-5)
  {
    int tid2 = tid - 256;
    if (tid2 >= 0 && tid2 < 128) {
      int mm = tid2 >> 3, jj = (tid2 & 7) * 8;
      *(uint4*)&X1[0][mm * 72 + jj] =
          *(const uint4*)&xc[((size_t)(bg + mm) * 512 + 0) * 64 + jj];
    }
  }
  __syncthreads();

  for (int t = 0; t < 512; ++t) {
    int pr = t & 1, pw = 1 - pr;
    if (wv < 4) {
      // L1: K = 64 x | 64 h1 -> kt 0,1 from X1[pr], kt 2,3 from H1[pr]
      f32x4 acc[4] = {};
#pragma unroll
      for (int kt = 0; kt < 4; ++kt) {
        const ushortT* ap = (kt < 2) ? &X1[pr][m * 72 + kt * 32 + koff]
                                     : &H1[pr][m * 72 + (kt - 2) * 32 + koff];
        bf16x8 a = *reinterpret_cast<const bf16x8*>(ap);
#pragma unroll
        for (int q = 0; q < 4; ++q)
          acc[q] = __builtin_amdgcn_mfma_f32_16x16x32_bf16(a, w1r[q][kt], acc[q], 0, 0, 0);
      }
#pragma unroll
      for (int r = 0; r < 4; ++r) {
        int row = (lane >> 4) * 4 + r;
        int lc = wv * 16 + col;
        float gi = acc[0][r] + b1v[0];
        float gf = acc[1][r] + b1v[1];
        float gg = acc[2][r] + b1v[2];
        float go = acc[3][r] + b1v[3];
        float c = fsig(gf) * C1[row * 64 + lc] + fsig(gi) * ftanh(gg);
        float h = fsig(go) * ftanh(c);
        C1[row * 64 + lc] = c;
        H1[pw][row * 72 + lc] = f2bf(h);
      }
    } else {
      // waves 4-5: prefetch xc(t+1)
      int tid2 = tid - 256;
      if (tid2 < 128 && t + 1 < 512) {
        int mm = tid2 >> 3, jj = (tid2 & 7) * 8;
        *(uint4*)&X1[pw][mm * 72 + jj] =
            *(const uint4*)&xc[((size_t)(bg + mm) * 512 + (t + 1)) * 64 + jj];
      }
    }
    __syncthreads();
    // L2: K = 64 h1(t) | 128 h2(t-1) -> kt 0,1 from H1[pw], kt 2..5 from H2[pr]
    {
      f32x4 acc[4] = {};
#pragma unroll
      for (int kt = 0; kt < 6; ++kt) {
        const ushortT* ap = (kt < 2) ? &H1[pw][m * 72 + kt * 32 + koff]
                                     : &H2[pr][m * 136 + (kt - 2) * 32 + koff];
        bf16x8 a = *reinterpret_cast<const bf16x8*>(ap);
#pragma unroll
        for (int q = 0; q < 4; ++q)
          acc[q] = __builtin_amdgcn_mfma_f32_16x16x32_bf16(a, w2r[q][kt], acc[q], 0, 0, 0);
      }
#pragma unroll
      for (int r = 0; r < 4; ++r) {
        int row = (lane >> 4) * 4 + r;
        int lc = wv * 16 + col;
        float gi = acc[0][r] + b2v[0];
        float gf = acc[1][r] + b2v[1];
        float gg = acc[2][r] + b2v[2];
        float go = acc[3][r] + b2v[3];
        float c = fsig(gf) * C2[row * 128 + lc] + fsig(gi) * ftanh(gg);
        float h = fsig(go) * ftanh(c);
        C2[row * 128 + lc] = c;
        ushortT hb = f2bf(h);
        H2[pw][row * 136 + lc] = hb;
        h2hist[((size_t)(g * 512 + t) * 16 + row) * 128 + lc] = hb;
      }
    }
    __syncthreads();
  }
}

// ---------------------------------------------------------------------------
// LSTM stage B: layer 3. 32 blocks x 512 thr; block (g,s) computes h3 cols
// [s*128,(s+1)*128). W3 frags pinned (192 VGPR). Exchange via tagged u32
// atomics (tag<<16|bf16), relaxed agent scope, parity double-buffered:
// writer at step t -> slot[(t+1)&1] tag t+1; reader at step t polls
// slot[t&1] for tag==t. Reuse distance 2 steps; max pair lead is 1 => safe.
// ---------------------------------------------------------------------------
__global__ __launch_bounds__(512, 2) void k_lstmB(const ushortT* __restrict__ h2hist,
                                                  const ushortT* __restrict__ Wcat,
                                                  const float* __restrict__ b3g,
                                                  ushortT* __restrict__ zbuf,
                                                  uint32_t* __restrict__ xbuf) {
  __shared__ ushortT HS[2][16 * 136];
  __shared__ float C3[16 * 128];
  int tid = threadIdx.x;
  int wv = tid >> 6, lane = tid & 63;
  int col = lane & 15, koff = (lane >> 4) * 8, m = lane & 15;
  int bx = blockIdx.x;
  int s = (bx >> 3) & 1;
  int g = (bx & 7) | ((bx >> 4) << 3);
  int ps = 1 - s;
  int bg = g * 16;
  const ushortT* W3 = Wcat + 131072;

  bf16x8 wB[4][12];
#pragma unroll
  for (int q = 0; q < 4; ++q)
#pragma unroll
    for (int k = 0; k < 12; ++k) {
      wB[q][k] = *reinterpret_cast<const bf16x8*>(
          &W3[(size_t)(q * 256 + s * 128 + wv * 16 + col) * 384 + k * 32 + koff]);
      PIN(wB[q][k]);
    }
  float b3v[4];
#pragma unroll
  for (int q = 0; q < 4; ++q) b3v[q] = b3g[q * 256 + s * 128 + wv * 16 + col];

  for (int i = tid; i < 2 * 16 * 136; i += 512) HS[0][i] = 0;
  for (int i = tid; i < 16 * 128; i += 512) C3[i] = 0.0f;
  __syncthreads();

  // xbuf layout: [g][half][parity][16 rows][128 cols] u32
  uint32_t* myslot = xbuf + (((size_t)g * 2 + s) * 2 + 0) * 2048;
  const uint32_t* pslot = xbuf + (((size_t)g * 2 + ps) * 2 + 0) * 2048;

  for (int t = 0; t < 512; ++t) {
    int pr = t & 1, pw = 1 - pr;
    f32x4 acc[4] = {};
    // h2(t) section: kt 0..3, A direct from global (L2-resident)
#pragma unroll
    for (int kt = 0; kt < 4; ++kt) {
      bf16x8 a = *reinterpret_cast<const bf16x8*>(
          &h2hist[((size_t)(g * 512 + t) * 16 + m) * 128 + kt * 32 + koff]);
#pragma unroll
      for (int q = 0; q < 4; ++q)
        acc[q] = __builtin_amdgcn_mfma_f32_16x16x32_bf16(a, wB[q][kt], acc[q], 0, 0, 0);
    }
    if (t > 0) {
      // own h3 half from LDS (written by our epilogue last step)
#pragma unroll
      for (int j = 0; j < 4; ++j) {
        bf16x8 a = *reinterpret_cast<const bf16x8*>(&HS[pr][m * 136 + j * 32 + koff]);
#pragma unroll
        for (int q = 0; q < 4; ++q)
          acc[q] = __builtin_amdgcn_mfma_f32_16x16x32_bf16(a, wB[q][4 + s * 4 + j], acc[q], 0, 0, 0);
      }
      // partner half: poll tagged words (tag==t), parity slot t&1
      const uint32_t* pb = pslot + (size_t)(t & 1) * 2048 + m * 128 + koff;
      uint32_t vb[4][8];
#pragma unroll
      for (int j = 0; j < 4; ++j)
#pragma unroll
        for (int i = 0; i < 8; ++i)
          vb[j][i] = __hip_atomic_load(pb + j * 32 + i, __ATOMIC_RELAXED,
                                       __HIP_MEMORY_SCOPE_AGENT);
      for (;;) {
        bool ok = true;
#pragma unroll
        for (int j = 0; j < 4; ++j)
#pragma unroll
          for (int i = 0; i < 8; ++i)
            if ((vb[j][i] >> 16) != (uint32_t)t) {
              ok = false;
              vb[j][i] = __hip_atomic_load(pb + j * 32 + i, __ATOMIC_RELAXED,
                                           __HIP_MEMORY_SCOPE_AGENT);
            }
        if (ok) break;
      }
#pragma unroll
      for (int j = 0; j < 4; ++j) {
        u32x4 pk;
#pragma unroll
        for (int p2 = 0; p2 < 4; ++p2)
          pk[p2] = (vb[j][2 * p2] & 0xffffu) | (vb[j][2 * p2 + 1] << 16);
        bf16x8 a = __builtin_bit_cast(bf16x8, pk);
#pragma unroll
        for (int q = 0; q < 4; ++q)
          acc[q] = __builtin_amdgcn_mfma_f32_16x16x32_bf16(a, wB[q][4 + ps * 4 + j], acc[q], 0, 0, 0);
      }
    }
    // epilogue: gates -> c,h ; h to LDS (own next-step A), zbuf (fc1), xbuf (partner)
    uint32_t* mw = myslot + (size_t)((t + 1) & 1) * 2048;
#pragma unroll
    for (int r = 0; r < 4; ++r) {
      int row = (lane >> 4) * 4 + r;
      int lc = wv * 16 + col;
      float gi = acc[0][r] + b3v[0];
      float gf = acc[1][r] + b3v[1];
      float gg = acc[2][r] + b3v[2];
      float go = acc[3][r] + b3v[3];
      float c = fsig(gf) * C3[row * 128 + lc] + fsig(gi) * ftanh(gg);
      float h = fsig(go) * ftanh(c);
      C3[row * 128 + lc] = c;
      ushortT hb = f2bf(h);
      HS[pw][row * 136 + lc] = hb;
      zbuf[((size_t)(bg + row) * 512 + t) * 256 + s * 128 + lc] = hb;
      __hip_atomic_store(mw + row * 128 + lc, ((uint32_t)(t + 1) << 16) | hb,
                         __ATOMIC_RELAXED, __HIP_MEMORY_SCOPE_AGENT);
    }
    __syncthreads();  // HS[pw]/C3 visible block-wide before next step
  }
}

// ---------------------------------------------------------------------------
// fc1: split-K MFMA. grid (kb=64, nb=4); block computes [256m x 64n] partial
// over a 2048-K chunk; W transposed fp32->bf16 through LDS.
// ---------------------------------------------------------------------------
__global__ __launch_bounds__(256) void k_fc1(const ushortT* __restrict__ zbuf,
                                             const float* __restrict__ w,
                                             float* __restrict__ part) {
  __shared__ ushortT As[256 * 40];
  __shared__ ushortT Bs[64 * 40];
  int tid = threadIdx.x;
  int kb = blockIdx.x;  // 0..63
  int nb = blockIdx.y;  // 0..3
  int wv = tid >> 6, lane = tid & 63;
  int col = lane & 15, koff = (lane >> 4) * 8;
  int k0base = kb * 2048;
  f32x4 acc[4][4] = {};
  for (int kt = 0; kt < 64; ++kt) {
    int k0 = k0base + kt * 32;
    {
      const uint4* src = (const uint4*)(zbuf + (size_t)tid * 131072 + k0);
      uint4* dst = (uint4*)(As + tid * 40);
      dst[0] = src[0]; dst[1] = src[1]; dst[2] = src[2]; dst[3] = src[3];
    }
    {
      int kk = tid >> 3, j0 = (tid & 7) * 8;
      const float* srcw = w + (size_t)(k0 + kk) * 256 + nb * 64 + j0;
#pragma unroll
      for (int jj = 0; jj < 8; ++jj) Bs[(j0 + jj) * 40 + kk] = f2bf(srcw[jj]);
    }
    __syncthreads();
    bf16x8 bfr[4];
#pragma unroll
    for (int nt = 0; nt < 4; ++nt)
      bfr[nt] = *reinterpret_cast<const bf16x8*>(&Bs[(nt * 16 + col) * 40 + koff]);
#pragma unroll
    for (int mt = 0; mt < 4; ++mt) {
      bf16x8 afr = *reinterpret_cast<const bf16x8*>(&As[(wv * 64 + mt * 16 + col) * 40 + koff]);
#pragma unroll
      for (int nt = 0; nt < 4; ++nt)
        acc[mt][nt] = __builtin_amdgcn_mfma_f32_16x16x32_bf16(afr, bfr[nt], acc[mt][nt], 0, 0, 0);
    }
    __syncthreads();
  }
#pragma unroll
  for (int mt = 0; mt < 4; ++mt)
#pragma unroll
    for (int nt = 0; nt < 4; ++nt)
#pragma unroll
      for (int r = 0; r < 4; ++r) {
        int m = wv * 64 + mt * 16 + (lane >> 4) * 4 + r;
        int n = nb * 64 + nt * 16 + col;
        part[(size_t)kb * 65536 + m * 256 + n] = acc[mt][nt][r];
      }
}

__global__ void k_fc1red(const float* __restrict__ part, const float* __restrict__ b,
                         float* __restrict__ out) {
  int id = blockIdx.x * 256 + threadIdx.x;
  if (id >= 65536) return;
  float s = 0.0f;
  for (int kb = 0; kb < 64; ++kb) s += part[(size_t)kb * 65536 + id];
  s += b[id & 255];
  out[id] = fmaxf(s, 0.0f);
}

__global__ void k_fcv(const float* __restrict__ in, const float* __restrict__ w,
                      const float* __restrict__ b, float* __restrict__ out,
                      int K, int Nn, int doRelu) {
  int id = blockIdx.x * 256 + threadIdx.x;
  int m = id / Nn, n = id % Nn;
  float s = b[n];
  for (int k = 0; k < K; ++k) s += in[m * K + k] * w[k * Nn + n];
  if (doRelu) s = fmaxf(s, 0.0f);
  out[id] = s;
}

// ---------------------------------------------------------------------------
extern "C" void kernel_launch(void* const* d_in, const int* in_sizes, int n_in,
                              void* d_out, int out_size, void* d_ws, size_t ws_size,
                              hipStream_t stream) {
  (void)in_sizes; (void)n_in; (void)out_size; (void)ws_size;
  const float* x    = (const float*)d_in[0];
  const int* ei     = (const int*)d_in[1];
  const float* ew   = (const float*)d_in[2];
  const float* c1w0 = (const float*)d_in[4];
  const float* c1w1 = (const float*)d_in[5];
  const float* c1b  = (const float*)d_in[6];
  const float* c2w0 = (const float*)d_in[7];
  const float* c2w1 = (const float*)d_in[8];
  const float* c2b  = (const float*)d_in[9];
  const float* l1wi = (const float*)d_in[10];
  const float* l1wh = (const float*)d_in[11];
  const float* l1b  = (const float*)d_in[12];
  const float* l2wi = (const float*)d_in[13];
  const float* l2wh = (const float*)d_in[14];
  const float* l2b  = (const float*)d_in[15];
  const float* l3wi = (const float*)d_in[16];
  const float* l3wh = (const float*)d_in[17];
  const float* l3b  = (const float*)d_in[18];
  const float* fc1w = (const float*)d_in[19];
  const float* fc1b = (const float*)d_in[20];
  const float* fc2w = (const float*)d_in[21];
  const float* fc2b = (const float*)d_in[22];
  const float* fc3w = (const float*)d_in[23];
  const float* fc3b = (const float*)d_in[24];
  const float* fc4w = (const float*)d_in[25];
  const float* fc4b = (const float*)d_in[26];
  float* out = (float*)d_out;

  char* p = (char*)d_ws;
  auto alloc = [&](size_t bytes) { void* r = (void*)p; p += (bytes + 255) & ~(size_t)255; return r; };
  float* xt      = (float*)alloc(32505856);    // [T][N][16]  (reused as h2hist)
  float* h1buf   = (float*)alloc(32505856);    // conv1 out   (part of reuse window)
  float* dinv    = (float*)alloc(2031616);     // deg -> rsqrt in place
  int* counts    = (int*)alloc(2031616);
  int* offs      = (int*)alloc(2031616);
  int* fillc     = (int*)alloc(2031616);
  int* ctot      = (int*)alloc(8192);
  int* cbase     = (int*)alloc(8192);
  int* csrs      = (int*)alloc(25600000);
  float* csrn    = (float*)alloc(25600000);
  ushortT* xc    = (ushortT*)alloc(16777216);  // [B][512][64] bf16 (pad 62->64)
  ushortT* Wcat  = (ushortT*)alloc(1048576);
  ushortT* zbuf  = (ushortT*)alloc(67108864);  // [B][512][256] bf16
  float* part    = (float*)alloc(16777216);    // fc1 partials [64][256][256]
  float* fo1     = (float*)alloc(262144);
  float* fo2     = (float*)alloc(131072);
  float* fo3     = (float*)alloc(65536);
  uint32_t* xbuf = (uint32_t*)alloc(524288);   // [16][2][2 parity][2048] u32
  // h2hist [16 groups][512 t][16 rows][128] bf16 = 33.5 MB; xt+h1buf (65 MB)
  // are dead after the k_gc pair -> reuse that region.
  ushortT* h2hist = (ushortT*)xt;

  hipMemsetAsync(dinv, 0, 2031616, stream);
  hipMemsetAsync(counts, 0, 2031616, stream);
  hipMemsetAsync(fillc, 0, 2031616, stream);
  hipMemsetAsync(xc, 0, 16777216, stream);
  // xbuf needs no init: harness poisons d_ws with 0xAA -> tag 0xAAAA never
  // matches any live tag (1..512).

  k_wprep<<<2048, 256, 0, stream>>>(l1wi, l1wh, l2wi, l2wh, l3wi, l3wh, Wcat);
  k_transpose<<<15872, 256, 0, stream>>>(x, xt);
  k_degcount<<<25000, 256, 0, stream>>>(ei, ew, dinv, counts);
  k_dinv<<<1984, 256, 0, stream>>>(dinv);
  k_scanA<<<1984, 256, 0, stream>>>(counts, offs, ctot);
  k_scanB<<<1, 256, 0, stream>>>(ctot, cbase);
  k_scanC<<<1984, 256, 0, stream>>>(offs, cbase);
  k_fill<<<25000, 256, 0, stream>>>(ei, ew, dinv, offs, fillc, csrs, csrn);
  k_gc<<<1984, 256, 0, stream>>>(xt, offs, csrs, csrn, c1w0, c1w1, c1b, h1buf, nullptr, 0);
  k_gc<<<1984, 256, 0, stream>>>(h1buf, offs, csrs, csrn, c2w0, c2w1, c2b, nullptr, xc, 1);
  k_lstmA<<<16, 512, 0, stream>>>(xc, Wcat, l1b, l2b, h2hist);
  k_lstmB<<<32, 512, 0, stream>>>(h2hist, Wcat, l3b, zbuf, xbuf);
  k_fc1<<<dim3(64, 4), 256, 0, stream>>>(zbuf, fc1w, part);
  k_fc1red<<<256, 256, 0, stream>>>(part, fc1b, fo1);
  k_fcv<<<128, 256, 0, stream>>>(fo1, fc2w, fc2b, fo2, 256, 128, 1);
  k_fcv<<<64, 256, 0, stream>>>(fo2, fc3w, fc3b, fo3, 128, 64, 1);
  k_fcv<<<4, 256, 0, stream>>>(fo3, fc4w, fc4b, out, 64, 4, 0);
}

// Round 4
// 8146.014 us; speedup vs baseline: 1.3780x; 1.3780x over previous
//
#include <hip/hip_runtime.h>
#include <cstdint>
#include <cstddef>

// ---------------------------------------------------------------------------
// GCN(Cheb K=2, x2) -> 3-layer LSTM -> MLP head, MI355X gfx950.
// R4: __launch_bounds__(512, *1*) on LSTM kernels — R3's (512,2) forced a
//     128-VGPR cap (4 waves/SIMD), so PIN'd weight frags were spilled and
//     re-streamed (VGPR_Count=76 both rounds). With 2 waves/SIMD the 256-VGPR
//     budget fits the 192-VGPR W3 residency.
//     Exchange: 256 threads poll exactly the 2048 tagged partner words into
//     an LDS staging tile (was: every thread polling 32 words, 8x redundant).
// ---------------------------------------------------------------------------

#define T_DIM 32
#define F_DIMC 16
#define NNODE 15872
#define EDGES 200000
#define BATCH 256
#define SEQL 512
#define TN (T_DIM * NNODE)   // 507904
#define TE (T_DIM * EDGES)   // 6400000

typedef unsigned short ushortT;
typedef __bf16 bf16_t;
typedef bf16_t bf16x8 __attribute__((ext_vector_type(8)));
typedef float f32x4 __attribute__((ext_vector_type(4)));

__device__ __forceinline__ ushortT f2bf(float f) {
  union { float f; unsigned u; } v; v.f = f;
  unsigned u = v.u;
  u += 0x7fffu + ((u >> 16) & 1u);
  return (ushortT)(u >> 16);
}
__device__ __forceinline__ float fsig(float x) { return 1.0f / (1.0f + __expf(-x)); }
__device__ __forceinline__ float ftanh(float x) {
  float e = __expf(2.0f * x);
  return 1.0f - 2.0f / (e + 1.0f);
}
#define PIN(v) asm volatile("" : "+v"(v))

// ---------------------------------------------------------------------------
// Weight prep: Wcat1 [256][128] = [wih1(62,pad2) | whh1(64)]
//              Wcat2 [512][192] = [wih2(64) | whh2(128)]
//              Wcat3 [1024][384] = [wih3(128) | whh3(256)]   (bf16, row = gate)
// ---------------------------------------------------------------------------
__global__ void k_wprep(const float* __restrict__ w1i, const float* __restrict__ w1h,
                        const float* __restrict__ w2i, const float* __restrict__ w2h,
                        const float* __restrict__ w3i, const float* __restrict__ w3h,
                        ushortT* __restrict__ Wcat) {
  int id = blockIdx.x * 256 + threadIdx.x;
  if (id >= 524288) return;
  float v;
  if (id < 32768) {
    int g = id >> 7, k = id & 127;
    v = (k < 62) ? w1i[g * 62 + k] : ((k >= 64) ? w1h[g * 64 + (k - 64)] : 0.0f);
  } else if (id < 131072) {
    int j = id - 32768; int g = j / 192, k = j % 192;
    v = (k < 64) ? w2i[g * 64 + k] : w2h[g * 128 + (k - 64)];
  } else {
    int j = id - 131072; int g = j / 384, k = j % 384;
    v = (k < 128) ? w3i[g * 128 + k] : w3h[g * 256 + (k - 128)];
  }
  Wcat[id] = f2bf(v);
}

// x [N][F][T] -> xt [T][N][F], LDS-tiled per node row
__global__ void k_transpose(const float* __restrict__ x, float* __restrict__ xt) {
  __shared__ float s[528];  // 16 x 33
  int n = blockIdx.x;
  int tid = threadIdx.x;
  for (int i = tid; i < 512; i += 256) {
    s[(i >> 5) * 33 + (i & 31)] = x[(size_t)n * 512 + i];
  }
  __syncthreads();
  for (int i = tid; i < 512; i += 256) {
    int t = i >> 4, f = i & 15;
    xt[((size_t)t * NNODE + n) * 16 + f] = s[f * 33 + t];
  }
}

// per-edge: deg[src] += w ; counts[dst] += 1
__global__ void k_degcount(const int* __restrict__ ei, const float* __restrict__ ew,
                           float* __restrict__ deg, int* __restrict__ counts) {
  int id = blockIdx.x * 256 + threadIdx.x;
  if (id >= TE) return;
  int t = id / EDGES, e = id % EDGES;
  int src = ei[(2 * t) * EDGES + e];
  int dst = ei[(2 * t + 1) * EDGES + e];
  atomicAdd(&deg[t * NNODE + src], ew[id]);
  atomicAdd(&counts[t * NNODE + dst], 1);
}

__global__ void k_dinv(float* __restrict__ deg) {
  int id = blockIdx.x * 256 + threadIdx.x;
  if (id >= TN) return;
  float d = deg[id];
  deg[id] = (d > 0.0f) ? rsqrtf(d) : 0.0f;
}

// block-local exclusive scan of counts (256-chunks), chunk totals out
__global__ void k_scanA(const int* __restrict__ counts, int* __restrict__ offs,
                        int* __restrict__ ctot) {
  __shared__ int s[256];
  int tid = threadIdx.x;
  int gid = blockIdx.x * 256 + tid;
  int v = counts[gid];
  s[tid] = v; __syncthreads();
  for (int off = 1; off < 256; off <<= 1) {
    int x = (tid >= off) ? s[tid - off] : 0;
    __syncthreads();
    s[tid] += x;
    __syncthreads();
  }
  offs[gid] = s[tid] - v;
  if (tid == 255) ctot[blockIdx.x] = s[255];
}

// single-block scan of 1984 chunk totals
__global__ void k_scanB(const int* __restrict__ ctot, int* __restrict__ cbase) {
  __shared__ int s[256];
  int tid = threadIdx.x;
  int carry = 0;
  for (int c = 0; c < 8; ++c) {
    int i = c * 256 + tid;
    int v = (i < 1984) ? ctot[i] : 0;
    s[tid] = v; __syncthreads();
    for (int off = 1; off < 256; off <<= 1) {
      int x = (tid >= off) ? s[tid - off] : 0;
      __syncthreads();
      s[tid] += x;
      __syncthreads();
    }
    if (i < 1984) cbase[i] = carry + s[tid] - v;
    int tot = s[255];
    __syncthreads();
    carry += tot;
  }
}

__global__ void k_scanC(int* __restrict__ offs, const int* __restrict__ cbase) {
  int id = blockIdx.x * 256 + threadIdx.x;
  if (id >= TN) return;
  offs[id] += cbase[id >> 8];
}

// scatter edges into CSR slots: csr_src[pos], csr_nrm[pos]
__global__ void k_fill(const int* __restrict__ ei, const float* __restrict__ ew,
                       const float* __restrict__ dinv, const int* __restrict__ offs,
                       int* __restrict__ fillc, int* __restrict__ csrs,
                       float* __restrict__ csrn) {
  int id = blockIdx.x * 256 + threadIdx.x;
  if (id >= TE) return;
  int t = id / EDGES, e = id % EDGES;
  int src = ei[(2 * t) * EDGES + e];
  int dst = ei[(2 * t + 1) * EDGES + e];
  int idx = t * NNODE + dst;
  int pos = offs[idx] + atomicAdd(&fillc[idx], 1);
  csrs[pos] = src;
  csrn[pos] = -dinv[t * NNODE + src] * ew[id] * dinv[idx];
}

__device__ __forceinline__ void fma4(float4& a, float sc, const float4 b) {
  a.x += sc * b.x; a.y += sc * b.y; a.z += sc * b.z; a.w += sc * b.w;
}

// gather (tx1) + combine: out = x@w0 + tx1@w1 + b [+leaky] ; mode1 writes xc bf16
__global__ void k_gc(const float* __restrict__ in, const int* __restrict__ offs,
                     const int* __restrict__ csrs, const float* __restrict__ csrn,
                     const float* __restrict__ w0, const float* __restrict__ w1,
                     const float* __restrict__ bias, float* __restrict__ outF,
                     ushortT* __restrict__ outX, int mode) {
  __shared__ float sw0[256], sw1[256], sb[16];
  int tid = threadIdx.x;
  sw0[tid] = w0[tid];
  sw1[tid] = w1[tid];
  if (tid < 16) sb[tid] = bias[tid];
  __syncthreads();
  int idx = blockIdx.x * 256 + tid;
  if (idx >= TN) return;
  int t = idx / NNODE, n = idx % NNODE;
  const float4* rowp = (const float4*)(in + (size_t)idx * 16);
  float4 x0 = rowp[0], x1 = rowp[1], x2 = rowp[2], x3 = rowp[3];
  float4 a0 = {0, 0, 0, 0}, a1 = {0, 0, 0, 0}, a2 = {0, 0, 0, 0}, a3 = {0, 0, 0, 0};
  int beg = offs[idx];
  int end = (idx == TN - 1) ? TE : offs[idx + 1];
  const float* base = in + (size_t)t * NNODE * 16;
  for (int p2 = beg; p2 < end; ++p2) {
    int s = csrs[p2];
    float nr = csrn[p2];
    const float4* rp = (const float4*)(base + (size_t)s * 16);
    fma4(a0, nr, rp[0]); fma4(a1, nr, rp[1]); fma4(a2, nr, rp[2]); fma4(a3, nr, rp[3]);
  }
  float xr[16], ar[16];
  *(float4*)&xr[0] = x0; *(float4*)&xr[4] = x1; *(float4*)&xr[8] = x2; *(float4*)&xr[12] = x3;
  *(float4*)&ar[0] = a0; *(float4*)&ar[4] = a1; *(float4*)&ar[8] = a2; *(float4*)&ar[12] = a3;
  float o[16];
#pragma unroll
  for (int j = 0; j < 16; ++j) o[j] = sb[j];
#pragma unroll
  for (int k = 0; k < 16; ++k) {
    float xv = xr[k], av = ar[k];
#pragma unroll
    for (int j = 0; j < 16; ++j) o[j] += xv * sw0[k * 16 + j] + av * sw1[k * 16 + j];
  }
  if (mode == 0) {
#pragma unroll
    for (int j = 0; j < 16; ++j) o[j] = (o[j] > 0.0f) ? o[j] : 0.01f * o[j];
    float4* op = (float4*)(outF + (size_t)idx * 16);
    op[0] = *(float4*)&o[0]; op[1] = *(float4*)&o[4];
    op[2] = *(float4*)&o[8]; op[3] = *(float4*)&o[12];
  } else {
    int bb = n / 62, ch = n % 62;
#pragma unroll
    for (int j = 0; j < 16; ++j)
      outX[((size_t)(bb * 512 + t * 16 + j)) * 64 + ch] = f2bf(o[j]);
  }
}

// ---------------------------------------------------------------------------
// LSTM stage A: layers 1+2. 16 blocks x 512 thr (8 waves), 1 block/CU so the
// allocator has 256 VGPRs (2 waves/SIMD). W1 (waves 0-3) + W2 (all) pinned.
// h2(t) written to h2hist [g][t][16][128] bf16 for stage B.
// ---------------------------------------------------------------------------
__global__ __launch_bounds__(512, 1) void k_lstmA(const ushortT* __restrict__ xc,
                                                  const ushortT* __restrict__ Wcat,
                                                  const float* __restrict__ b1g,
                                                  const float* __restrict__ b2g,
                                                  ushortT* __restrict__ h2hist) {
  __shared__ ushortT X1[2][16 * 72];
  __shared__ ushortT H1[2][16 * 72];
  __shared__ ushortT H2[2][16 * 136];
  __shared__ float C1[16 * 64];
  __shared__ float C2[16 * 128];
  int tid = threadIdx.x;
  int wv = tid >> 6, lane = tid & 63;
  int col = lane & 15, koff = (lane >> 4) * 8, m = lane & 15;
  int g = blockIdx.x;
  int bg = g * 16;
  const ushortT* W1 = Wcat;
  const ushortT* W2 = Wcat + 32768;

  bf16x8 w1r[4][4];
  if (wv < 4) {
#pragma unroll
    for (int q = 0; q < 4; ++q)
#pragma unroll
      for (int k = 0; k < 4; ++k) {
        w1r[q][k] = *reinterpret_cast<const bf16x8*>(
            &W1[(size_t)(q * 64 + wv * 16 + col) * 128 + k * 32 + koff]);
        PIN(w1r[q][k]);
      }
  }
  bf16x8 w2r[4][6];
#pragma unroll
  for (int q = 0; q < 4; ++q)
#pragma unroll
    for (int k = 0; k < 6; ++k) {
      w2r[q][k] = *reinterpret_cast<const bf16x8*>(
          &W2[(size_t)(q * 128 + wv * 16 + col) * 192 + k * 32 + koff]);
      PIN(w2r[q][k]);
    }
  float b1v[4] = {0, 0, 0, 0}, b2v[4];
  if (wv < 4) {
#pragma unroll
    for (int q = 0; q < 4; ++q) b1v[q] = b1g[q * 64 + wv * 16 + col];
  }
#pragma unroll
  for (int q = 0; q < 4; ++q) b2v[q] = b2g[q * 128 + wv * 16 + col];

  for (int i = tid; i < 2 * 16 * 72; i += 512) { X1[0][i] = 0; H1[0][i] = 0; }
  for (int i = tid; i < 2 * 16 * 136; i += 512) H2[0][i] = 0;
  for (int i = tid; i < 16 * 64; i += 512) C1[i] = 0.0f;
  for (int i = tid; i < 16 * 128; i += 512) C2[i] = 0.0f;
  __syncthreads();
  // prestage xc(t=0) into X1 parity 0 (waves 4-5)
  {
    int tid2 = tid - 256;
    if (tid2 >= 0 && tid2 < 128) {
      int mm = tid2 >> 3, jj = (tid2 & 7) * 8;
      *(uint4*)&X1[0][mm * 72 + jj] =
          *(const uint4*)&xc[((size_t)(bg + mm) * 512 + 0) * 64 + jj];
    }
  }
  __syncthreads();

  for (int t = 0; t < 512; ++t) {
    int pr = t & 1, pw = 1 - pr;
    if (wv < 4) {
      // L1: K = 64 x | 64 h1 -> kt 0,1 from X1[pr], kt 2,3 from H1[pr]
      f32x4 acc[4] = {};
#pragma unroll
      for (int kt = 0; kt < 4; ++kt) {
        const ushortT* ap = (kt < 2) ? &X1[pr][m * 72 + kt * 32 + koff]
                                     : &H1[pr][m * 72 + (kt - 2) * 32 + koff];
        bf16x8 a = *reinterpret_cast<const bf16x8*>(ap);
#pragma unroll
        for (int q = 0; q < 4; ++q)
          acc[q] = __builtin_amdgcn_mfma_f32_16x16x32_bf16(a, w1r[q][kt], acc[q], 0, 0, 0);
      }
#pragma unroll
      for (int r = 0; r < 4; ++r) {
        int row = (lane >> 4) * 4 + r;
        int lc = wv * 16 + col;
        float gi = acc[0][r] + b1v[0];
        float gf = acc[1][r] + b1v[1];
        float gg = acc[2][r] + b1v[2];
        float go = acc[3][r] + b1v[3];
        float c = fsig(gf) * C1[row * 64 + lc] + fsig(gi) * ftanh(gg);
        float h = fsig(go) * ftanh(c);
        C1[row * 64 + lc] = c;
        H1[pw][row * 72 + lc] = f2bf(h);
      }
    } else {
      // waves 4-5: prefetch xc(t+1)
      int tid2 = tid - 256;
      if (tid2 < 128 && t + 1 < 512) {
        int mm = tid2 >> 3, jj = (tid2 & 7) * 8;
        *(uint4*)&X1[pw][mm * 72 + jj] =
            *(const uint4*)&xc[((size_t)(bg + mm) * 512 + (t + 1)) * 64 + jj];
      }
    }
    __syncthreads();
    // L2: K = 64 h1(t) | 128 h2(t-1) -> kt 0,1 from H1[pw], kt 2..5 from H2[pr]
    {
      f32x4 acc[4] = {};
#pragma unroll
      for (int kt = 0; kt < 6; ++kt) {
        const ushortT* ap = (kt < 2) ? &H1[pw][m * 72 + kt * 32 + koff]
                                     : &H2[pr][m * 136 + (kt - 2) * 32 + koff];
        bf16x8 a = *reinterpret_cast<const bf16x8*>(ap);
#pragma unroll
        for (int q = 0; q < 4; ++q)
          acc[q] = __builtin_amdgcn_mfma_f32_16x16x32_bf16(a, w2r[q][kt], acc[q], 0, 0, 0);
      }
#pragma unroll
      for (int r = 0; r < 4; ++r) {
        int row = (lane >> 4) * 4 + r;
        int lc = wv * 16 + col;
        float gi = acc[0][r] + b2v[0];
        float gf = acc[1][r] + b2v[1];
        float gg = acc[2][r] + b2v[2];
        float go = acc[3][r] + b2v[3];
        float c = fsig(gf) * C2[row * 128 + lc] + fsig(gi) * ftanh(gg);
        float h = fsig(go) * ftanh(c);
        C2[row * 128 + lc] = c;
        ushortT hb = f2bf(h);
        H2[pw][row * 136 + lc] = hb;
        h2hist[((size_t)(g * 512 + t) * 16 + row) * 128 + lc] = hb;
      }
    }
    __syncthreads();
  }
}

// ---------------------------------------------------------------------------
// LSTM stage B: layer 3. 32 blocks x 512 thr, 1 block/CU (256-VGPR budget).
// Block (g,s) computes h3 cols [s*128,(s+1)*128); W3 frags pinned (192 VGPR).
// Exchange: tagged u32 (tag<<16|bf16), relaxed agent scope (LLC-coherent,
// XCD-placement independent), parity double-buffered. 256 threads poll the
// 2048 partner words into LDS tile PS; all waves consume from LDS.
// ---------------------------------------------------------------------------
__global__ __launch_bounds__(512, 1) void k_lstmB(const ushortT* __restrict__ h2hist,
                                                  const ushortT* __restrict__ Wcat,
                                                  const float* __restrict__ b3g,
                                                  ushortT* __restrict__ zbuf,
                                                  uint32_t* __restrict__ xbuf) {
  __shared__ ushortT HS[2][16 * 136];
  __shared__ ushortT PS[16 * 136];
  __shared__ float C3[16 * 128];
  int tid = threadIdx.x;
  int wv = tid >> 6, lane = tid & 63;
  int col = lane & 15, koff = (lane >> 4) * 8, m = lane & 15;
  int bx = blockIdx.x;
  int s = (bx >> 3) & 1;
  int g = (bx & 7) | ((bx >> 4) << 3);
  int ps = 1 - s;
  int bg = g * 16;
  const ushortT* W3 = Wcat + 131072;

  bf16x8 wB[4][12];
#pragma unroll
  for (int q = 0; q < 4; ++q)
#pragma unroll
    for (int k = 0; k < 12; ++k) {
      wB[q][k] = *reinterpret_cast<const bf16x8*>(
          &W3[(size_t)(q * 256 + s * 128 + wv * 16 + col) * 384 + k * 32 + koff]);
      PIN(wB[q][k]);
    }
  float b3v[4];
#pragma unroll
  for (int q = 0; q < 4; ++q) b3v[q] = b3g[q * 256 + s * 128 + wv * 16 + col];

  for (int i = tid; i < 2 * 16 * 136; i += 512) HS[0][i] = 0;
  for (int i = tid; i < 16 * 128; i += 512) C3[i] = 0.0f;
  __syncthreads();

  // xbuf layout: [g][half][parity][16 rows][128 cols] u32
  uint32_t* myslot = xbuf + (((size_t)g * 2 + s) * 2) * 2048;
  const uint32_t* pslot = xbuf + (((size_t)g * 2 + ps) * 2) * 2048;

  for (int t = 0; t < 512; ++t) {
    int pr = t & 1, pw = 1 - pr;
    f32x4 acc[4] = {};
    // phase A: h2(t) (kt 0..3) + own h3 half (from LDS HS)
#pragma unroll
    for (int kt = 0; kt < 4; ++kt) {
      bf16x8 a = *reinterpret_cast<const bf16x8*>(
          &h2hist[((size_t)(g * 512 + t) * 16 + m) * 128 + kt * 32 + koff]);
#pragma unroll
      for (int q = 0; q < 4; ++q)
        acc[q] = __builtin_amdgcn_mfma_f32_16x16x32_bf16(a, wB[q][kt], acc[q], 0, 0, 0);
    }
    if (t > 0) {
#pragma unroll
      for (int j = 0; j < 4; ++j) {
        bf16x8 a = *reinterpret_cast<const bf16x8*>(&HS[pr][m * 136 + j * 32 + koff]);
#pragma unroll
        for (int q = 0; q < 4; ++q)
          acc[q] = __builtin_amdgcn_mfma_f32_16x16x32_bf16(a, wB[q][4 + s * 4 + j], acc[q], 0, 0, 0);
      }
      // 256 threads fetch the 2048 partner words (batched poll) -> PS
      if (tid < 256) {
        int row = tid >> 4, c0 = (tid & 15) * 8;
        const uint32_t* pb = pslot + (size_t)(t & 1) * 2048 + row * 128 + c0;
        uint32_t v[8];
#pragma unroll
        for (int i = 0; i < 8; ++i)
          v[i] = __hip_atomic_load(pb + i, __ATOMIC_RELAXED, __HIP_MEMORY_SCOPE_AGENT);
        for (;;) {
          bool ok = true;
#pragma unroll
          for (int i = 0; i < 8; ++i)
            if ((v[i] >> 16) != (uint32_t)t) {
              ok = false;
              v[i] = __hip_atomic_load(pb + i, __ATOMIC_RELAXED, __HIP_MEMORY_SCOPE_AGENT);
            }
          if (ok) break;
        }
#pragma unroll
        for (int i = 0; i < 8; ++i)
          PS[row * 136 + c0 + i] = (ushortT)(v[i] & 0xffffu);
      }
      __syncthreads();
      // phase B: partner h3 half from PS
#pragma unroll
      for (int j = 0; j < 4; ++j) {
        bf16x8 a = *reinterpret_cast<const bf16x8*>(&PS[m * 136 + j * 32 + koff]);
#pragma unroll
        for (int q = 0; q < 4; ++q)
          acc[q] = __builtin_amdgcn_mfma_f32_16x16x32_bf16(a, wB[q][4 + ps * 4 + j], acc[q], 0, 0, 0);
      }
    }
    // epilogue: gates -> c,h ; h to LDS (own), zbuf (fc1), xbuf (partner)
    uint32_t* mw = myslot + (size_t)((t + 1) & 1) * 2048;
#pragma unroll
    for (int r = 0; r < 4; ++r) {
      int row = (lane >> 4) * 4 + r;
      int lc = wv * 16 + col;
      float gi = acc[0][r] + b3v[0];
      float gf = acc[1][r] + b3v[1];
      float gg = acc[2][r] + b3v[2];
      float go = acc[3][r] + b3v[3];
      float c = fsig(gf) * C3[row * 128 + lc] + fsig(gi) * ftanh(gg);
      float h = fsig(go) * ftanh(c);
      C3[row * 128 + lc] = c;
      ushortT hb = f2bf(h);
      HS[pw][row * 136 + lc] = hb;
      zbuf[((size_t)(bg + row) * 512 + t) * 256 + s * 128 + lc] = hb;
      __hip_atomic_store(mw + row * 128 + lc, ((uint32_t)(t + 1) << 16) | hb,
                         __ATOMIC_RELAXED, __HIP_MEMORY_SCOPE_AGENT);
    }
    __syncthreads();  // HS[pw]/C3/PS reuse safe before next step
  }
}

// ---------------------------------------------------------------------------
// fc1: split-K MFMA. grid (kb=64, nb=4); block computes [256m x 64n] partial
// over a 2048-K chunk; W transposed fp32->bf16 through LDS.
// ---------------------------------------------------------------------------
__global__ __launch_bounds__(256) void k_fc1(const ushortT* __restrict__ zbuf,
                                             const float* __restrict__ w,
                                             float* __restrict__ part) {
  __shared__ ushortT As[256 * 40];
  __shared__ ushortT Bs[64 * 40];
  int tid = threadIdx.x;
  int kb = blockIdx.x;  // 0..63
  int nb = blockIdx.y;  // 0..3
  int wv = tid >> 6, lane = tid & 63;
  int col = lane & 15, koff = (lane >> 4) * 8;
  int k0base = kb * 2048;
  f32x4 acc[4][4] = {};
  for (int kt = 0; kt < 64; ++kt) {
    int k0 = k0base + kt * 32;
    {
      const uint4* src = (const uint4*)(zbuf + (size_t)tid * 131072 + k0);
      uint4* dst = (uint4*)(As + tid * 40);
      dst[0] = src[0]; dst[1] = src[1]; dst[2] = src[2]; dst[3] = src[3];
    }
    {
      int kk = tid >> 3, j0 = (tid & 7) * 8;
      const float* srcw = w + (size_t)(k0 + kk) * 256 + nb * 64 + j0;
#pragma unroll
      for (int jj = 0; jj < 8; ++jj) Bs[(j0 + jj) * 40 + kk] = f2bf(srcw[jj]);
    }
    __syncthreads();
    bf16x8 bfr[4];
#pragma unroll
    for (int nt = 0; nt < 4; ++nt)
      bfr[nt] = *reinterpret_cast<const bf16x8*>(&Bs[(nt * 16 + col) * 40 + koff]);
#pragma unroll
    for (int mt = 0; mt < 4; ++mt) {
      bf16x8 afr = *reinterpret_cast<const bf16x8*>(&As[(wv * 64 + mt * 16 + col) * 40 + koff]);
#pragma unroll
      for (int nt = 0; nt < 4; ++nt)
        acc[mt][nt] = __builtin_amdgcn_mfma_f32_16x16x32_bf16(afr, bfr[nt], acc[mt][nt], 0, 0, 0);
    }
    __syncthreads();
  }
#pragma unroll
  for (int mt = 0; mt < 4; ++mt)
#pragma unroll
    for (int nt = 0; nt < 4; ++nt)
#pragma unroll
      for (int r = 0; r < 4; ++r) {
        int m = wv * 64 + mt * 16 + (lane >> 4) * 4 + r;
        int n = nb * 64 + nt * 16 + col;
        part[(size_t)kb * 65536 + m * 256 + n] = acc[mt][nt][r];
      }
}

__global__ void k_fc1red(const float* __restrict__ part, const float* __restrict__ b,
                         float* __restrict__ out) {
  int id = blockIdx.x * 256 + threadIdx.x;
  if (id >= 65536) return;
  float s = 0.0f;
  for (int kb = 0; kb < 64; ++kb) s += part[(size_t)kb * 65536 + id];
  s += b[id & 255];
  out[id] = fmaxf(s, 0.0f);
}

__global__ void k_fcv(const float* __restrict__ in, const float* __restrict__ w,
                      const float* __restrict__ b, float* __restrict__ out,
                      int K, int Nn, int doRelu) {
  int id = blockIdx.x * 256 + threadIdx.x;
  int m = id / Nn, n = id % Nn;
  float s = b[n];
  for (int k = 0; k < K; ++k) s += in[m * K + k] * w[k * Nn + n];
  if (doRelu) s = fmaxf(s, 0.0f);
  out[id] = s;
}

// ---------------------------------------------------------------------------
extern "C" void kernel_launch(void* const* d_in, const int* in_sizes, int n_in,
                              void* d_out, int out_size, void* d_ws, size_t ws_size,
                              hipStream_t stream) {
  (void)in_sizes; (void)n_in; (void)out_size; (void)ws_size;
  const float* x    = (const float*)d_in[0];
  const int* ei     = (const int*)d_in[1];
  const float* ew   = (const float*)d_in[2];
  const float* c1w0 = (const float*)d_in[4];
  const float* c1w1 = (const float*)d_in[5];
  const float* c1b  = (const float*)d_in[6];
  const float* c2w0 = (const float*)d_in[7];
  const float* c2w1 = (const float*)d_in[8];
  const float* c2b  = (const float*)d_in[9];
  const float* l1wi = (const float*)d_in[10];
  const float* l1wh = (const float*)d_in[11];
  const float* l1b  = (const float*)d_in[12];
  const float* l2wi = (const float*)d_in[13];
  const float* l2wh = (const float*)d_in[14];
  const float* l2b  = (const float*)d_in[15];
  const float* l3wi = (const float*)d_in[16];
  const float* l3wh = (const float*)d_in[17];
  const float* l3b  = (const float*)d_in[18];
  const float* fc1w = (const float*)d_in[19];
  const float* fc1b = (const float*)d_in[20];
  const float* fc2w = (const float*)d_in[21];
  const float* fc2b = (const float*)d_in[22];
  const float* fc3w = (const float*)d_in[23];
  const float* fc3b = (const float*)d_in[24];
  const float* fc4w = (const float*)d_in[25];
  const float* fc4b = (const float*)d_in[26];
  float* out = (float*)d_out;

  char* p = (char*)d_ws;
  auto alloc = [&](size_t bytes) { void* r = (void*)p; p += (bytes + 255) & ~(size_t)255; return r; };
  float* xt      = (float*)alloc(32505856);    // [T][N][16]  (reused as h2hist)
  float* h1buf   = (float*)alloc(32505856);    // conv1 out   (part of reuse window)
  float* dinv    = (float*)alloc(2031616);     // deg -> rsqrt in place
  int* counts    = (int*)alloc(2031616);
  int* offs      = (int*)alloc(2031616);
  int* fillc     = (int*)alloc(2031616);
  int* ctot      = (int*)alloc(8192);
  int* cbase     = (int*)alloc(8192);
  int* csrs      = (int*)alloc(25600000);
  float* csrn    = (float*)alloc(25600000);
  ushortT* xc    = (ushortT*)alloc(16777216);  // [B][512][64] bf16 (pad 62->64)
  ushortT* Wcat  = (ushortT*)alloc(1048576);
  ushortT* zbuf  = (ushortT*)alloc(67108864);  // [B][512][256] bf16
  float* part    = (float*)alloc(16777216);    // fc1 partials [64][256][256]
  float* fo1     = (float*)alloc(262144);
  float* fo2     = (float*)alloc(131072);
  float* fo3     = (float*)alloc(65536);
  uint32_t* xbuf = (uint32_t*)alloc(524288);   // [16][2][2 parity][2048] u32
  // h2hist [16 groups][512 t][16 rows][128] bf16 = 33.5 MB; xt+h1buf (65 MB)
  // are dead after the k_gc pair -> reuse that region.
  ushortT* h2hist = (ushortT*)xt;

  hipMemsetAsync(dinv, 0, 2031616, stream);
  hipMemsetAsync(counts, 0, 2031616, stream);
  hipMemsetAsync(fillc, 0, 2031616, stream);
  hipMemsetAsync(xc, 0, 16777216, stream);
  // xbuf needs no init: harness poisons d_ws with 0xAA -> tag 0xAAAA never
  // matches any live tag (1..512).

  k_wprep<<<2048, 256, 0, stream>>>(l1wi, l1wh, l2wi, l2wh, l3wi, l3wh, Wcat);
  k_transpose<<<15872, 256, 0, stream>>>(x, xt);
  k_degcount<<<25000, 256, 0, stream>>>(ei, ew, dinv, counts);
  k_dinv<<<1984, 256, 0, stream>>>(dinv);
  k_scanA<<<1984, 256, 0, stream>>>(counts, offs, ctot);
  k_scanB<<<1, 256, 0, stream>>>(ctot, cbase);
  k_scanC<<<1984, 256, 0, stream>>>(offs, cbase);
  k_fill<<<25000, 256, 0, stream>>>(ei, ew, dinv, offs, fillc, csrs, csrn);
  k_gc<<<1984, 256, 0, stream>>>(xt, offs, csrs, csrn, c1w0, c1w1, c1b, h1buf, nullptr, 0);
  k_gc<<<1984, 256, 0, stream>>>(h1buf, offs, csrs, csrn, c2w0, c2w1, c2b, nullptr, xc, 1);
  k_lstmA<<<16, 512, 0, stream>>>(xc, Wcat, l1b, l2b, h2hist);
  k_lstmB<<<32, 512, 0, stream>>>(h2hist, Wcat, l3b, zbuf, xbuf);
  k_fc1<<<dim3(64, 4), 256, 0, stream>>>(zbuf, fc1w, part);
  k_fc1red<<<256, 256, 0, stream>>>(part, fc1b, fo1);
  k_fcv<<<128, 256, 0, stream>>>(fo1, fc2w, fc2b, fo2, 256, 128, 1);
  k_fcv<<<64, 256, 0, stream>>>(fo2, fc3w, fc3b, fo3, 128, 64, 1);
  k_fcv<<<4, 256, 0, stream>>>(fo3, fc4w, fc4b, out, 64, 4, 0);
}